// Round 14
// baseline (527.127 us; speedup 1.0000x reference)
//
#include <hip/hip_runtime.h>

#define NU_ 100000
#define NI_ 50000
#define NA_ 5000
#define FEAT_ 256
#define H_ 128
#define ER_ 1000000
#define ES_ 500000
#define EH_ 250000

#define NTOT_ (3 * NI_ + NU_ + NA_)      // 255000 combined nodes
#define RTOT_ (2 * ER_ + ES_ + 2 * EH_)  // 3,000,000 records
#define NSB_ ((NTOT_ + 1023) / 1024)     // 250 super-buckets (1024 nodes each)
// node-space bases (order defines pool layout)
#define B_RI 0
#define B_RU (NI_)
#define B_SI (NI_ + NU_)
#define B_HA (2 * NI_ + NU_)
#define B_HI (2 * NI_ + NU_ + NA_)

typedef long long i64;
typedef unsigned short u16;
typedef unsigned int u32;
typedef __attribute__((ext_vector_type(8))) short bf16x8;
typedef __attribute__((ext_vector_type(4))) float f32x4;

__device__ __forceinline__ u16 f2bf(float v) {           // round-to-nearest-even
    u32 b = __float_as_uint(v);
    b += 0x7fff + ((b >> 16) & 1);
    return (u16)(b >> 16);
}
__device__ __forceinline__ float bf2f(u16 v) {
    return __uint_as_float((u32)v << 16);
}

// record r -> (node, val). val < 2^17 (ids < 100000), node < 255000.
__device__ __forceinline__ void rec_of(int r, const int* __restrict__ er,
                                       const int* __restrict__ es,
                                       const int* __restrict__ eh,
                                       int& node, int& val) {
    if (r < 2 * ER_) {
        int e = r >> 1;
        if ((r & 1) == 0) { node = B_RI + er[ER_ + e]; val = er[e]; }
        else              { node = B_RU + er[e];       val = er[ER_ + e]; }
    } else if (r < 2 * ER_ + ES_) {
        int e = r - 2 * ER_;
        node = B_SI + es[ES_ + e]; val = es[e];
    } else {
        int q = r - 2 * ER_ - ES_;
        int e = q >> 1;
        if ((q & 1) == 0) { node = B_HA + eh[EH_ + e]; val = eh[e]; }
        else              { node = B_HI + eh[e];       val = eh[EH_ + e]; }
    }
}

// init SB cursors to fixed strided bases; zero the off1 sentinel
__global__ __launch_bounds__(256) void sbinit_kernel(int* __restrict__ sbc,
                                                     int* __restrict__ OFF) {
    int t = threadIdx.x;
    sbc[t] = t << 16;          // region base = sb * 65536
    if (t < 4) OFF[t] = 0;     // sentinel (off1[-1] = 0)
}

// ---- weight prep struct ----
struct WJob {
    const float* s0; const float* s1; const float* s2;
    int logK; int base;
};
struct WJobs { WJob j[17]; };

// ---- misc pack: binA (blocks [0,nblkA)) || tobf (nblkT) || wsplit (nblkW) ----
// All low-VGPR memory-class ops, mutually independent.
__global__ __launch_bounds__(256) void packed_misc_kernel(
    const int* __restrict__ er, const int* __restrict__ es, const int* __restrict__ eh,
    int* __restrict__ sbc, int* __restrict__ cpool, int nblkA,
    const float4* __restrict__ inU, ushort4* __restrict__ outU, long n4u,
    const float4* __restrict__ inA, ushort4* __restrict__ outA, long n4a, int nblkT,
    WJobs jobs, int wtotal, u16* __restrict__ WTH, u16* __restrict__ WTL) {
    __shared__ int h[256];
    __shared__ int gof[256];
    int b = blockIdx.x;
    int t = threadIdx.x;
    if (b < nblkA) {
        // ---- binA: LDS-binned scatter into per-SB fixed regions ----
        h[t] = 0;
        __syncthreads();
        int base = b * 4096;
        int sbs[16];
        u32 recs[16];
#pragma unroll
        for (int i = 0; i < 16; ++i) {
            int r = base + i * 256 + t;
            sbs[i] = -1;
            if (r < RTOT_) {
                int node, val;
                rec_of(r, er, es, eh, node, val);
                int sb = node >> 10;
                sbs[i] = sb;
                recs[i] = ((u32)(node & 1023) << 17) | (u32)val;
                atomicAdd(&h[sb], 1);
            }
        }
        __syncthreads();
        {
            int c = h[t];
            if (c > 0) gof[t] = atomicAdd(&sbc[t], c);
            h[t] = 0;   // reuse as block-local cursor
        }
        __syncthreads();
#pragma unroll
        for (int i = 0; i < 16; ++i) {
            if (sbs[i] >= 0) {
                int slot = atomicAdd(&h[sbs[i]], 1);
                cpool[gof[sbs[i]] + slot] = (int)recs[i];
            }
        }
        return;
    }
    b -= nblkA;
    if (b < nblkT) {
        // ---- tobf: fp32 -> bf16 embedding tables ----
        long i = (long)b * 256 + t;
        const float4* in; ushort4* out;
        if (i < n4u) { in = inU + i; out = outU + i; }
        else if (i < n4u + n4a) { in = inA + (i - n4u); out = outA + (i - n4u); }
        else return;
        float4 v = *in;
        ushort4 o;
        o.x = f2bf(v.x); o.y = f2bf(v.y); o.z = f2bf(v.z); o.w = f2bf(v.w);
        *out = o;
        return;
    }
    b -= nblkT;
    {
        // ---- wsplit: W -> frag-tiled bf16 (hi/lo for logK==8; RTN else) ----
        int gid = b * 256 + t;
        if (gid >= wtotal) return;
        int ji = 0;
        for (int i = 1; i < 17; ++i)
            if (gid >= jobs.j[i].base) ji = i;
        WJob jb = jobs.j[ji];
        int local = gid - jb.base;
        int e = local & 7;
        int l = (local >> 3) & 63;
        int nt = (local >> 9) & 7;
        int kc = local >> 12;
        int n = nt * 16 + (l & 15);
        int k = kc * 32 + ((l >> 4) << 3) + e;
        i64 si = (i64)k * 128 + n;
        float v = jb.s0[si];
        if (jb.s1 != nullptr) v += jb.s1[si] + jb.s2[si];
        if (jb.logK == 8) {
            u32 bb = __float_as_uint(v);
            u16 hh = (u16)(bb >> 16);             // truncation split: v = hi + lo
            float rem = v - __uint_as_float(bb & 0xffff0000u);
            WTH[gid] = hh;
            WTL[gid] = (u16)(__float_as_uint(rem) >> 16);
        } else {
            WTH[gid] = f2bf(v);                   // single RTN bf16
        }
    }
}

// ---- pass 2: per-SB counts -> exclusive scan -> SBB dense bases ----
__global__ __launch_bounds__(256) void sbscan_kernel(const int* __restrict__ sbc,
                                                     int* __restrict__ sbb) {
    int t = threadIdx.x;
    int v = (t < NSB_) ? (sbc[t] - (t << 16)) : 0;
    int incl = v;
    int lane = t & 63;
#pragma unroll
    for (int d = 1; d < 64; d <<= 1) {
        int u = __shfl_up(incl, d);
        if (lane >= d) incl += u;
    }
    __shared__ int wsum[4];
    if (lane == 63) wsum[t >> 6] = incl;
    __syncthreads();
    int wo = 0;
    for (int i = 0; i < (t >> 6); ++i) wo += wsum[i];
    if (t < NSB_) sbb[t] = wo + incl - v;
}

// ---- pass 3: one 1024-thread block per SB; histogram -> scan -> off1 -> place ----
__global__ __launch_bounds__(1024) void binB_kernel(const int* __restrict__ cpool,
                                                    const int* __restrict__ sbb,
                                                    const int* __restrict__ sbc,
                                                    int* __restrict__ off1,
                                                    int* __restrict__ pool) {
    __shared__ int c[1024];
    __shared__ int b[1024];
    __shared__ int wsum[16];
    int sb = blockIdx.x, t = threadIdx.x;
    int rlo = sb << 16, rhi = sbc[sb];
    int base = sbb[sb];
    c[t] = 0;
    __syncthreads();
    for (int j = rlo + t; j < rhi; j += 1024)
        atomicAdd(&c[((u32)cpool[j]) >> 17], 1);
    __syncthreads();
    int v = c[t];
    int incl = v;
    int lane = t & 63;
#pragma unroll
    for (int d = 1; d < 64; d <<= 1) {
        int u = __shfl_up(incl, d);
        if (lane >= d) incl += u;
    }
    if (lane == 63) wsum[t >> 6] = incl;
    __syncthreads();
    int wo = 0;
    for (int i = 0; i < (t >> 6); ++i) wo += wsum[i];
    int ex = wo + incl - v;
    int node = sb * 1024 + t;
    if (node < NTOT_) off1[node] = base + ex + v;   // inclusive end
    b[t] = base + ex;                               // cursor
    __syncthreads();
    for (int j = rlo + t; j < rhi; j += 1024) {
        u32 rec = (u32)cpool[j];
        int pos = atomicAdd(&b[rec >> 17], 1);
        pool[pos] = (int)(rec & 0x1FFFF);
    }
}

#define ACC8(A, V)                                                            \
    {                                                                         \
        A[0] += bf2f((u16)(V.x & 0xffff)); A[1] += bf2f((u16)(V.x >> 16));    \
        A[2] += bf2f((u16)(V.y & 0xffff)); A[3] += bf2f((u16)(V.y >> 16));    \
        A[4] += bf2f((u16)(V.z & 0xffff)); A[5] += bf2f((u16)(V.z >> 16));    \
        A[6] += bf2f((u16)(V.w & 0xffff)); A[7] += bf2f((u16)(V.w >> 16));    \
    }

// ---- packed gather: ONE WAVE PER ROW (no degree divergence across rows).
// 64 lanes = 4 edge-groups x 16 col-lanes; 8 edges in flight (2 guarded loads);
// cross-group shfl_xor reduce; lanes 0-15 write the 256B row. ----
struct GOp {
    const u16* feat; const int* off1c; u16* agg;
    int nblk; int n; int pad0; int pad1; int pad2;
};
struct GOps { GOp op[5]; };

__global__ __launch_bounds__(256) void packed_gather_kernel(GOps ops, int nops,
                                                            const int* __restrict__ pool) {
    int b = blockIdx.x;
    int i = 0;
    while (i < nops - 1 && b >= ops.op[i].nblk) { b -= ops.op[i].nblk; ++i; }
    GOp o = ops.op[i];
    int t = threadIdx.x;
    int row = b * 4 + (t >> 6);          // one wave per row
    if (row >= o.n) return;
    int l = t & 63;
    int eg = l >> 4;                     // edge group 0..3
    int lane = (l & 15) * 8;             // col base
    int start = o.off1c[row - 1];
    int end = o.off1c[row];
    const u16* feat = o.feat;
    float a0[8], a1[8];
#pragma unroll
    for (int k = 0; k < 8; ++k) { a0[k] = 0.f; a1[k] = 0.f; }
    for (int j0 = start; j0 < end; j0 += 8) {
        int ja = j0 + eg, jb = j0 + 4 + eg;
        if (ja < end) {
            int s = pool[ja];
            uint4 v = *(const uint4*)&feat[(i64)s * H_ + lane];
            ACC8(a0, v);
        }
        if (jb < end) {
            int s = pool[jb];
            uint4 v = *(const uint4*)&feat[(i64)s * H_ + lane];
            ACC8(a1, v);
        }
    }
#pragma unroll
    for (int k = 0; k < 8; ++k) {
        float s = a0[k] + a1[k];
        s += __shfl_xor(s, 16);
        s += __shfl_xor(s, 32);
        a0[k] = s;
    }
    if (eg == 0) {
        float inv = 1.0f / fmaxf((float)(end - start), 1.0f);
        uint4 o4;
        o4.x = (u32)f2bf(a0[0] * inv) | ((u32)f2bf(a0[1] * inv) << 16);
        o4.y = (u32)f2bf(a0[2] * inv) | ((u32)f2bf(a0[3] * inv) << 16);
        o4.z = (u32)f2bf(a0[4] * inv) | ((u32)f2bf(a0[5] * inv) << 16);
        o4.w = (u32)f2bf(a0[6] * inv) | ((u32)f2bf(a0[7] * inv) << 16);
        *(uint4*)&o.agg[(i64)row * H_ + lane] = o4;
    }
}

// ---- x_item GEMM: fp32 A (K=256), 3-term hi/lo split, bf16 out ----
__device__ __forceinline__ void split8(const float* f, bf16x8& h, bf16x8& lo) {
#pragma unroll
    for (int i = 0; i < 8; ++i) {
        u32 b = __float_as_uint(f[i]);
        h[i] = (short)(u16)(b >> 16);
        float rem = f[i] - __uint_as_float(b & 0xffff0000u);
        lo[i] = (short)(u16)(__float_as_uint(rem) >> 16);
    }
}

__global__ __launch_bounds__(256) void mgemm_x_kernel(
    const float* __restrict__ A, const u16* __restrict__ Wh, const u16* __restrict__ Wl,
    const float* __restrict__ bias, u16* __restrict__ Cbf, int M) {
    int t = threadIdx.x;
    int w = t >> 6, l = t & 63;
    int lr = l & 15, lq = l >> 4;
    int m0 = blockIdx.x * 128 + w * 32;

    f32x4 acc[2][8];
#pragma unroll
    for (int mt = 0; mt < 2; ++mt)
#pragma unroll
        for (int nt = 0; nt < 8; ++nt) acc[mt][nt] = (f32x4){0.f, 0.f, 0.f, 0.f};

    for (int kc = 0; kc < 8; ++kc) {   // K = 256
        bf16x8 ah0, al0, ah1, al1;
        {
            int row = m0 + lr;
            float f[8];
            if (row < M) {
                const float* ap = &A[(i64)row * FEAT_ + kc * 32 + lq * 8];
                *(float4*)&f[0] = *(const float4*)ap;
                *(float4*)&f[4] = *(const float4*)(ap + 4);
            } else {
#pragma unroll
                for (int i = 0; i < 8; ++i) f[i] = 0.f;
            }
            split8(f, ah0, al0);
        }
        {
            int row = m0 + 16 + lr;
            float f[8];
            if (row < M) {
                const float* ap = &A[(i64)row * FEAT_ + kc * 32 + lq * 8];
                *(float4*)&f[0] = *(const float4*)ap;
                *(float4*)&f[4] = *(const float4*)(ap + 4);
            } else {
#pragma unroll
                for (int i = 0; i < 8; ++i) f[i] = 0.f;
            }
            split8(f, ah1, al1);
        }
        const u16* whp = Wh + ((i64)kc * 8) * 512 + (i64)l * 8;
        const u16* wlp = Wl + ((i64)kc * 8) * 512 + (i64)l * 8;
#pragma unroll
        for (int nt = 0; nt < 8; ++nt) {
            bf16x8 bh = *(const bf16x8*)(whp + nt * 512);
            bf16x8 bl = *(const bf16x8*)(wlp + nt * 512);
            acc[0][nt] = __builtin_amdgcn_mfma_f32_16x16x32_bf16(ah0, bh, acc[0][nt], 0, 0, 0);
            acc[1][nt] = __builtin_amdgcn_mfma_f32_16x16x32_bf16(ah1, bh, acc[1][nt], 0, 0, 0);
            acc[0][nt] = __builtin_amdgcn_mfma_f32_16x16x32_bf16(al0, bh, acc[0][nt], 0, 0, 0);
            acc[1][nt] = __builtin_amdgcn_mfma_f32_16x16x32_bf16(al1, bh, acc[1][nt], 0, 0, 0);
            acc[0][nt] = __builtin_amdgcn_mfma_f32_16x16x32_bf16(ah0, bl, acc[0][nt], 0, 0, 0);
            acc[1][nt] = __builtin_amdgcn_mfma_f32_16x16x32_bf16(ah1, bl, acc[1][nt], 0, 0, 0);
        }
    }
#pragma unroll
    for (int nt = 0; nt < 8; ++nt) {
        int col = nt * 16 + lr;
        float bb = bias[col];
#pragma unroll
        for (int mt = 0; mt < 2; ++mt) {
#pragma unroll
            for (int r = 0; r < 4; ++r) {
                int row = m0 + mt * 16 + (lq << 2) + r;
                if (row < M) Cbf[(i64)row * H_ + col] = f2bf(acc[mt][nt][r] + bb);
            }
        }
    }
}

// ---- packed dual GEMM kernel: bf16 A (K=128 each), single RTN bf16 W ----
struct MOp {
    const u16* A1; const u16* W1; const u16* A2; const u16* W2;
    const float* b1; const float* b2;
    float* C; u16* Cbf;
    int nblk; int n; int fuse; int pad;
};
struct MOps { MOp op[5]; };

__global__ __launch_bounds__(256) void packed_gemm_kernel(
    MOps ops, int nops,
    const float* __restrict__ alpha, const float* __restrict__ fu,
    const float* __restrict__ fi, float* __restrict__ fout,
    float* __restrict__ wout) {
    int blk = blockIdx.x;
    int i = 0;
    while (i < nops - 1 && blk >= ops.op[i].nblk) { blk -= ops.op[i].nblk; ++i; }
    MOp o = ops.op[i];
    int t = threadIdx.x;
    int w = t >> 6, l = t & 63;
    int lr = l & 15, lq = l >> 4;
    int m0 = blk * 128 + w * 32;
    int M = o.n;

    f32x4 acc[2][8];
#pragma unroll
    for (int mt = 0; mt < 2; ++mt)
#pragma unroll
        for (int nt = 0; nt < 8; ++nt) acc[mt][nt] = (f32x4){0.f, 0.f, 0.f, 0.f};

#pragma unroll
    for (int mat = 0; mat < 2; ++mat) {
        const u16* A = mat ? o.A2 : o.A1;
        const u16* W = mat ? o.W2 : o.W1;
#pragma unroll
        for (int kc = 0; kc < 4; ++kc) {   // K = 128
            bf16x8 a0 = {0, 0, 0, 0, 0, 0, 0, 0}, a1 = {0, 0, 0, 0, 0, 0, 0, 0};
            int row0 = m0 + lr, row1 = m0 + 16 + lr;
            if (row0 < M) a0 = *(const bf16x8*)&A[(i64)row0 * H_ + kc * 32 + lq * 8];
            if (row1 < M) a1 = *(const bf16x8*)&A[(i64)row1 * H_ + kc * 32 + lq * 8];
            const u16* wp = W + ((i64)kc * 8) * 512 + (i64)l * 8;
#pragma unroll
            for (int nt = 0; nt < 8; ++nt) {
                bf16x8 bw = *(const bf16x8*)(wp + nt * 512);
                acc[0][nt] = __builtin_amdgcn_mfma_f32_16x16x32_bf16(a0, bw, acc[0][nt], 0, 0, 0);
                acc[1][nt] = __builtin_amdgcn_mfma_f32_16x16x32_bf16(a1, bw, acc[1][nt], 0, 0, 0);
            }
        }
    }

    float w0 = 0.f, w1 = 0.f, w2 = 0.f;
    if (o.fuse) {
        float x0 = alpha[0], x1 = alpha[1], x2 = alpha[2];
        float mx = fmaxf(x0, fmaxf(x1, x2));
        float e0 = __expf(x0 - mx), e1 = __expf(x1 - mx), e2 = __expf(x2 - mx);
        float inv = 1.f / (e0 + e1 + e2);
        w0 = e0 * inv; w1 = e1 * inv; w2 = e2 * inv;
        if (blk == 0 && t == 0) { wout[0] = w0; wout[1] = w1; wout[2] = w2; }
    }

#pragma unroll
    for (int nt = 0; nt < 8; ++nt) {
        int col = nt * 16 + lr;
        float bb = 0.5f * (o.b1[col] + o.b2[col]);
#pragma unroll
        for (int mt = 0; mt < 2; ++mt) {
#pragma unroll
            for (int r = 0; r < 4; ++r) {
                int row = m0 + mt * 16 + (lq << 2) + r;
                if (row < M) {
                    i64 idx = (i64)row * H_ + col;
                    float v = fmaxf(0.5f * acc[mt][nt][r] + bb, 0.f);
                    if (o.C != nullptr) o.C[idx] = v;
                    if (o.Cbf != nullptr) o.Cbf[idx] = f2bf(v);
                    if (o.fuse) fout[idx] = w0 * fu[idx] + w1 * fi[idx] + w2 * v;
                }
            }
        }
    }
}

extern "C" void kernel_launch(void* const* d_in, const int* in_sizes, int n_in,
                              void* d_out, int out_size, void* d_ws, size_t ws_size,
                              hipStream_t stream) {
    const float* xif  = (const float*)d_in[0];
    const float* uemb = (const float*)d_in[1];
    const float* aemb = (const float*)d_in[2];
    const float* liW  = (const float*)d_in[3];
    const float* lib  = (const float*)d_in[4];
    const float* uiWl = (const float*)d_in[5];
    const float* uibl = (const float*)d_in[6];
    const float* uiWr = (const float*)d_in[7];
    const float* iiWl = (const float*)d_in[8];
    const float* iibl = (const float*)d_in[9];
    const float* iiWr = (const float*)d_in[10];
    const float* iaWl = (const float*)d_in[11];
    const float* iabl = (const float*)d_in[12];
    const float* iaWr = (const float*)d_in[13];
    const float* alpha = (const float*)d_in[14];
    const int* er = (const int*)d_in[15];
    const int* es = (const int*)d_in[16];
    const int* eh = (const int*)d_in[17];

    float* out = (float*)d_out;
    float* FUSED  = out;
    float* OUT_UI = out + (i64)NI_ * H_;
    float* OUT_II = out + (i64)2 * NI_ * H_;
    float* OUT_IA = out + (i64)3 * NI_ * H_;
    float* WOUT   = out + (i64)4 * NI_ * H_;

    // ---- workspace layout: bf16 region first (16B-aligned), then ints ----
    u16* u = (u16*)d_ws;
    i64 uo = 0;
    u16* WTH    = u + uo; uo += 294912;
    u16* WTL    = u + uo; uo += 294912;
    u16* X_bf   = u + uo; uo += (i64)NI_ * H_;
    u16* HIU_bf = u + uo; uo += (i64)NI_ * H_;   // UI L0 item out
    u16* HII_bf = u + uo; uo += (i64)NI_ * H_;   // II L0 item out
    u16* HIA_bf = u + uo; uo += (i64)NI_ * H_;   // IA L0 item out
    u16* HU1_bf = u + uo; uo += (i64)NU_ * H_;
    u16* HA1_bf = u + uo; uo += (i64)NA_ * H_;
    u16* UE_bf  = u + uo; uo += (i64)NU_ * H_;
    u16* AE_bf  = u + uo; uo += (i64)NA_ * H_;
    u16* AGG1 = u + uo; uo += (i64)NI_ * H_;     // rates->item (UE)
    u16* AGG2 = u + uo; uo += (i64)NU_ * H_;     // rates->user (X)
    u16* AGG3 = u + uo; uo += (i64)NI_ * H_;     // rates->item (HU1)
    u16* AGG4 = u + uo; uo += (i64)NI_ * H_;     // sim->item (X)
    u16* AGG5 = u + uo; uo += (i64)NI_ * H_;     // sim->item (HII)
    u16* AGG6 = u + uo; uo += (i64)NA_ * H_;     // has->attr (X)
    u16* AGG7 = u + uo; uo += (i64)NI_ * H_;     // has->item (AE)
    u16* AGG8 = u + uo; uo += (i64)NI_ * H_;     // has->item (HA1)

    int* ip = (int*)(u + uo);
    i64 io = 0;
    int* OFF   = ip + io; io += NTOT_ + 4;        // [0]=sentinel; off1 = OFF+1
    int* SBB   = ip + io; io += 256;
    int* SBC   = ip + io; io += 256;
    int* POOL  = ip + io; io += RTOT_;
    int* CPOOL = ip + io; io += (i64)NSB_ << 16;  // strided SB regions
    int* off1 = OFF + 1;

    // ---- weight-prep jobs ----
    const float* famWl[8] = {uiWl, uiWl, uiWl, iiWl, iiWl, iaWl, iaWl, iaWl};
    const float* famWr[8] = {uiWr, uiWr, uiWr, iiWr, iiWr, iaWr, iaWr, iaWr};
    const float* famBl[8] = {uibl, uibl, uibl, iibl, iibl, iabl, iabl, iabl};
    const int eidx[8] = {0, 1, 4, 0, 2, 0, 1, 5};
    const int sidx[8] = {3, 2, 7, 1, 3, 3, 2, 6};

    WJobs jobs;
    jobs.j[0] = {liW, nullptr, nullptr, 8, 0};
    int wtotal = 32768;
    for (int s = 0; s < 8; ++s) {
        jobs.j[1 + 2 * s] = {famWl[s] + (i64)eidx[s] * 16384, nullptr, nullptr, 7, wtotal};
        wtotal += 16384;
        jobs.j[2 + 2 * s] = {famWr[s] + (i64)eidx[s] * 16384,
                             famWl[s] + (i64)sidx[s] * 16384,
                             famWr[s] + (i64)sidx[s] * 16384, 7, wtotal};
        wtotal += 16384;
    }

    // ---- phase 1: sbinit; then binA || tobf || wsplit in ONE launch ----
    sbinit_kernel<<<1, 256, 0, stream>>>(SBC, OFF);
    long n4u = (long)NU_ * H_ / 4, n4a = (long)NA_ * H_ / 4;
    int nblkA = (RTOT_ + 4095) / 4096;               // 733
    int nblkT = (int)((n4u + n4a + 255) / 256);      // 13125
    int nblkW = (wtotal + 255) / 256;                // 1152
    packed_misc_kernel<<<nblkA + nblkT + nblkW, 256, 0, stream>>>(
        er, es, eh, SBC, CPOOL, nblkA,
        (const float4*)uemb, (ushort4*)UE_bf, n4u,
        (const float4*)aemb, (ushort4*)AE_bf, n4a, nblkT,
        jobs, wtotal, WTH, WTL);
    sbscan_kernel<<<1, 256, 0, stream>>>(SBC, SBB);
    binB_kernel<<<NSB_, 1024, 0, stream>>>(CPOOL, SBB, SBC, off1, POOL);

    // x_item = xif @ liW + lib  -> bf16 table
    mgemm_x_kernel<<<(NI_ + 127) / 128, 256, 0, stream>>>(xif, WTH, WTL, lib, X_bf, NI_);

    // ---- op builders ----
    auto mkg = [&](const u16* feat, int cbase, int n, u16* agg) {
        GOp o{};
        o.feat = feat; o.off1c = off1 + cbase; o.agg = agg;
        o.nblk = (n + 3) / 4; o.n = n;                   // one wave per row
        return o;
    };
    auto glaunch = [&](GOps& ops, int nops) {
        int grid = 0;
        for (int i = 0; i < nops; ++i) grid += ops.op[i].nblk;
        packed_gather_kernel<<<grid, 256, 0, stream>>>(ops, nops, POOL);
    };
    auto mkm = [&](int slot, const u16* agg, const u16* A2, float* C, u16* Cbf,
                   int M, int fuse) {
        MOp o{};
        o.A1 = agg;
        o.W1 = WTH + 32768 + (i64)(2 * slot) * 16384;
        o.A2 = A2;
        o.W2 = WTH + 32768 + (i64)(2 * slot + 1) * 16384;
        o.b1 = famBl[slot] + (i64)eidx[slot] * 128;
        o.b2 = famBl[slot] + (i64)sidx[slot] * 128;
        o.C = C; o.Cbf = Cbf;
        o.nblk = (M + 127) / 128; o.n = M; o.fuse = fuse;
        return o;
    };
    auto mlaunch = [&](MOps& ops, int nops) {
        int grid = 0;
        for (int i = 0; i < nops; ++i) grid += ops.op[i].nblk;
        packed_gemm_kernel<<<grid, 256, 0, stream>>>(ops, nops, alpha,
                                                     OUT_UI, OUT_II, FUSED, WOUT);
    };

    // ---- G-pack 1: all 5 layer-0 gathers (heavy rows first) ----
    {
        GOps g{};
        g.op[0] = mkg(X_bf, B_HA, NA_, AGG6);    // has->attr: 50 edges/row
        g.op[1] = mkg(UE_bf, B_RI, NI_, AGG1);   // rates->item (20/row)
        g.op[2] = mkg(X_bf, B_RU, NU_, AGG2);    // rates->user (10/row)
        g.op[3] = mkg(X_bf, B_SI, NI_, AGG4);    // sim->item (10/row)
        g.op[4] = mkg(AE_bf, B_HI, NI_, AGG7);   // has->item (5/row)
        glaunch(g, 5);
    }
    // ---- M-pack 1: all 5 layer-0 GEMMs ----
    {
        MOps m{};
        m.op[0] = mkm(1, AGG2, UE_bf, nullptr, HU1_bf, NU_, 0);
        m.op[1] = mkm(0, AGG1, X_bf, nullptr, HIU_bf, NI_, 0);
        m.op[2] = mkm(3, AGG4, X_bf, nullptr, HII_bf, NI_, 0);
        m.op[3] = mkm(6, AGG7, X_bf, nullptr, HIA_bf, NI_, 0);
        m.op[4] = mkm(5, AGG6, AE_bf, nullptr, HA1_bf, NA_, 0);
        mlaunch(m, 5);
    }
    // ---- G-pack 2: layer-1 gathers ----
    {
        GOps g{};
        g.op[0] = mkg(HU1_bf, B_RI, NI_, AGG3);
        g.op[1] = mkg(HII_bf, B_SI, NI_, AGG5);
        g.op[2] = mkg(HA1_bf, B_HI, NI_, AGG8);
        glaunch(g, 3);
    }
    // ---- M-pack 2: G2 -> OUT_UI, G4 -> OUT_II ----
    {
        MOps m{};
        m.op[0] = mkm(2, AGG3, HIU_bf, OUT_UI, nullptr, NI_, 0);
        m.op[1] = mkm(4, AGG5, HII_bf, OUT_II, nullptr, NI_, 0);
        mlaunch(m, 2);
    }
    // ---- M-pack 3: final GEMM + fused epilogue ----
    {
        MOps m{};
        m.op[0] = mkm(7, AGG8, HIA_bf, OUT_IA, nullptr, NI_, 1);
        mlaunch(m, 1);
    }
}

// Round 15
// 477.152 us; speedup vs baseline: 1.1047x; 1.1047x over previous
//
#include <hip/hip_runtime.h>

#define NU_ 100000
#define NI_ 50000
#define NA_ 5000
#define FEAT_ 256
#define H_ 128
#define ER_ 1000000
#define ES_ 500000
#define EH_ 250000

#define NTOT_ (3 * NI_ + NU_ + NA_)      // 255000 combined nodes
#define RTOT_ (2 * ER_ + ES_ + 2 * EH_)  // 3,000,000 records
#define NSB_ ((NTOT_ + 1023) / 1024)     // 250 super-buckets (1024 nodes each)
// node-space bases (order defines pool layout)
#define B_RI 0
#define B_RU (NI_)
#define B_SI (NI_ + NU_)
#define B_HA (2 * NI_ + NU_)
#define B_HI (2 * NI_ + NU_ + NA_)

typedef long long i64;
typedef unsigned short u16;
typedef unsigned int u32;
typedef __attribute__((ext_vector_type(8))) short bf16x8;
typedef __attribute__((ext_vector_type(4))) float f32x4;
typedef __attribute__((ext_vector_type(2))) float f32x2;

__device__ __forceinline__ u16 f2bf(float v) {           // round-to-nearest-even
    u32 b = __float_as_uint(v);
    b += 0x7fff + ((b >> 16) & 1);
    return (u16)(b >> 16);
}
__device__ __forceinline__ float bf2f(u16 v) {
    return __uint_as_float((u32)v << 16);
}
// u32 holding 2 bf16 (lo = col c, hi = col c+1) -> f32x2 {col c, col c+1}
__device__ __forceinline__ f32x2 u2f2(u32 v) {
    f32x2 r;
    r.x = __uint_as_float(v << 16);
    r.y = __uint_as_float(v & 0xffff0000u);
    return r;
}

// record r -> (node, val). val < 2^17 (ids < 100000), node < 255000.
__device__ __forceinline__ void rec_of(int r, const int* __restrict__ er,
                                       const int* __restrict__ es,
                                       const int* __restrict__ eh,
                                       int& node, int& val) {
    if (r < 2 * ER_) {
        int e = r >> 1;
        if ((r & 1) == 0) { node = B_RI + er[ER_ + e]; val = er[e]; }
        else              { node = B_RU + er[e];       val = er[ER_ + e]; }
    } else if (r < 2 * ER_ + ES_) {
        int e = r - 2 * ER_;
        node = B_SI + es[ES_ + e]; val = es[e];
    } else {
        int q = r - 2 * ER_ - ES_;
        int e = q >> 1;
        if ((q & 1) == 0) { node = B_HA + eh[EH_ + e]; val = eh[e]; }
        else              { node = B_HI + eh[e];       val = eh[EH_ + e]; }
    }
}

// init SB cursors to fixed strided bases; zero the off1 sentinel
__global__ __launch_bounds__(256) void sbinit_kernel(int* __restrict__ sbc,
                                                     int* __restrict__ OFF) {
    int t = threadIdx.x;
    sbc[t] = t << 16;          // region base = sb * 65536
    if (t < 4) OFF[t] = 0;     // sentinel (off1[-1] = 0)
}

// ---- weight prep struct ----
struct WJob {
    const float* s0; const float* s1; const float* s2;
    int logK; int base;
};
struct WJobs { WJob j[17]; };

// ---- misc pack: binA (blocks [0,nblkA)) || tobf (nblkT) || wsplit (nblkW) ----
__global__ __launch_bounds__(256) void packed_misc_kernel(
    const int* __restrict__ er, const int* __restrict__ es, const int* __restrict__ eh,
    int* __restrict__ sbc, int* __restrict__ cpool, int nblkA,
    const float4* __restrict__ inU, ushort4* __restrict__ outU, long n4u,
    const float4* __restrict__ inA, ushort4* __restrict__ outA, long n4a, int nblkT,
    WJobs jobs, int wtotal, u16* __restrict__ WTH, u16* __restrict__ WTL) {
    __shared__ int h[256];
    __shared__ int gof[256];
    int b = blockIdx.x;
    int t = threadIdx.x;
    if (b < nblkA) {
        // ---- binA: LDS-binned scatter into per-SB fixed regions ----
        h[t] = 0;
        __syncthreads();
        int base = b * 4096;
        int sbs[16];
        u32 recs[16];
#pragma unroll
        for (int i = 0; i < 16; ++i) {
            int r = base + i * 256 + t;
            sbs[i] = -1;
            if (r < RTOT_) {
                int node, val;
                rec_of(r, er, es, eh, node, val);
                int sb = node >> 10;
                sbs[i] = sb;
                recs[i] = ((u32)(node & 1023) << 17) | (u32)val;
                atomicAdd(&h[sb], 1);
            }
        }
        __syncthreads();
        {
            int c = h[t];
            if (c > 0) gof[t] = atomicAdd(&sbc[t], c);
            h[t] = 0;   // reuse as block-local cursor
        }
        __syncthreads();
#pragma unroll
        for (int i = 0; i < 16; ++i) {
            if (sbs[i] >= 0) {
                int slot = atomicAdd(&h[sbs[i]], 1);
                cpool[gof[sbs[i]] + slot] = (int)recs[i];
            }
        }
        return;
    }
    b -= nblkA;
    if (b < nblkT) {
        // ---- tobf: fp32 -> bf16 embedding tables ----
        long i = (long)b * 256 + t;
        const float4* in; ushort4* out;
        if (i < n4u) { in = inU + i; out = outU + i; }
        else if (i < n4u + n4a) { in = inA + (i - n4u); out = outA + (i - n4u); }
        else return;
        float4 v = *in;
        ushort4 o;
        o.x = f2bf(v.x); o.y = f2bf(v.y); o.z = f2bf(v.z); o.w = f2bf(v.w);
        *out = o;
        return;
    }
    b -= nblkT;
    {
        // ---- wsplit: W -> frag-tiled bf16 (hi/lo for logK==8; RTN else) ----
        int gid = b * 256 + t;
        if (gid >= wtotal) return;
        int ji = 0;
        for (int i = 1; i < 17; ++i)
            if (gid >= jobs.j[i].base) ji = i;
        WJob jb = jobs.j[ji];
        int local = gid - jb.base;
        int e = local & 7;
        int l = (local >> 3) & 63;
        int nt = (local >> 9) & 7;
        int kc = local >> 12;
        int n = nt * 16 + (l & 15);
        int k = kc * 32 + ((l >> 4) << 3) + e;
        i64 si = (i64)k * 128 + n;
        float v = jb.s0[si];
        if (jb.s1 != nullptr) v += jb.s1[si] + jb.s2[si];
        if (jb.logK == 8) {
            u32 bb = __float_as_uint(v);
            u16 hh = (u16)(bb >> 16);             // truncation split: v = hi + lo
            float rem = v - __uint_as_float(bb & 0xffff0000u);
            WTH[gid] = hh;
            WTL[gid] = (u16)(__float_as_uint(rem) >> 16);
        } else {
            WTH[gid] = f2bf(v);                   // single RTN bf16
        }
    }
}

// ---- pass 2: per-SB counts -> exclusive scan -> SBB dense bases ----
__global__ __launch_bounds__(256) void sbscan_kernel(const int* __restrict__ sbc,
                                                     int* __restrict__ sbb) {
    int t = threadIdx.x;
    int v = (t < NSB_) ? (sbc[t] - (t << 16)) : 0;
    int incl = v;
    int lane = t & 63;
#pragma unroll
    for (int d = 1; d < 64; d <<= 1) {
        int u = __shfl_up(incl, d);
        if (lane >= d) incl += u;
    }
    __shared__ int wsum[4];
    if (lane == 63) wsum[t >> 6] = incl;
    __syncthreads();
    int wo = 0;
    for (int i = 0; i < (t >> 6); ++i) wo += wsum[i];
    if (t < NSB_) sbb[t] = wo + incl - v;
}

// ---- pass 3: one 1024-thread block per SB; histogram -> scan -> off1 -> place ----
__global__ __launch_bounds__(1024) void binB_kernel(const int* __restrict__ cpool,
                                                    const int* __restrict__ sbb,
                                                    const int* __restrict__ sbc,
                                                    int* __restrict__ off1,
                                                    int* __restrict__ pool) {
    __shared__ int c[1024];
    __shared__ int b[1024];
    __shared__ int wsum[16];
    int sb = blockIdx.x, t = threadIdx.x;
    int rlo = sb << 16, rhi = sbc[sb];
    int base = sbb[sb];
    c[t] = 0;
    __syncthreads();
    for (int j = rlo + t; j < rhi; j += 1024)
        atomicAdd(&c[((u32)cpool[j]) >> 17], 1);
    __syncthreads();
    int v = c[t];
    int incl = v;
    int lane = t & 63;
#pragma unroll
    for (int d = 1; d < 64; d <<= 1) {
        int u = __shfl_up(incl, d);
        if (lane >= d) incl += u;
    }
    if (lane == 63) wsum[t >> 6] = incl;
    __syncthreads();
    int wo = 0;
    for (int i = 0; i < (t >> 6); ++i) wo += wsum[i];
    int ex = wo + incl - v;
    int node = sb * 1024 + t;
    if (node < NTOT_) off1[node] = base + ex + v;   // inclusive end
    b[t] = base + ex;                               // cursor
    __syncthreads();
    for (int j = rlo + t; j < rhi; j += 1024) {
        u32 rec = (u32)cpool[j];
        int pos = atomicAdd(&b[rec >> 17], 1);
        pool[pos] = (int)(rec & 0x1FFFF);
    }
}

// packed accumulate: 4 f32x2 (8 cols) += uint4 of 8 bf16, via v_pk_add_f32
#define ACCP(A, V)                                                            \
    {                                                                         \
        A[0] += u2f2(V.x); A[1] += u2f2(V.y);                                 \
        A[2] += u2f2(V.z); A[3] += u2f2(V.w);                                 \
    }

// ---- packed gather: 16 lanes/row, 4 rows/wave, 4-edge ILP (r13 mapping) ----
struct GOp {
    const u16* feat; const int* off1c; u16* agg;
    int nblk; int n; int pad0; int pad1; int pad2;
};
struct GOps { GOp op[5]; };

__global__ __launch_bounds__(256) void packed_gather_kernel(GOps ops, int nops,
                                                            const int* __restrict__ pool) {
    int b = blockIdx.x;
    int i = 0;
    while (i < nops - 1 && b >= ops.op[i].nblk) { b -= ops.op[i].nblk; ++i; }
    GOp o = ops.op[i];
    int row = b * 16 + (threadIdx.x >> 4);
    if (row >= o.n) return;
    int lane = (threadIdx.x & 15) * 8;
    int start = o.off1c[row - 1];
    int end = o.off1c[row];
    const u16* feat = o.feat;
    f32x2 a0[4], a1[4], a2[4], a3[4];
#pragma unroll
    for (int k = 0; k < 4; ++k) {
        a0[k] = (f32x2){0.f, 0.f}; a1[k] = (f32x2){0.f, 0.f};
        a2[k] = (f32x2){0.f, 0.f}; a3[k] = (f32x2){0.f, 0.f};
    }
    int j = start;
    for (; j + 4 <= end; j += 4) {
        int s0 = pool[j], s1 = pool[j + 1], s2 = pool[j + 2], s3 = pool[j + 3];
        uint4 v0 = *(const uint4*)&feat[(i64)s0 * H_ + lane];
        uint4 v1 = *(const uint4*)&feat[(i64)s1 * H_ + lane];
        uint4 v2 = *(const uint4*)&feat[(i64)s2 * H_ + lane];
        uint4 v3 = *(const uint4*)&feat[(i64)s3 * H_ + lane];
        ACCP(a0, v0); ACCP(a1, v1); ACCP(a2, v2); ACCP(a3, v3);
    }
    for (; j < end; ++j) {
        int s0 = pool[j];
        uint4 v0 = *(const uint4*)&feat[(i64)s0 * H_ + lane];
        ACCP(a0, v0);
    }
    float inv = 1.0f / fmaxf((float)(end - start), 1.0f);
    f32x2 iv = (f32x2){inv, inv};
    uint4 o4;
    f32x2 s;
    s = (a0[0] + a1[0] + a2[0] + a3[0]) * iv;
    o4.x = (u32)f2bf(s.x) | ((u32)f2bf(s.y) << 16);
    s = (a0[1] + a1[1] + a2[1] + a3[1]) * iv;
    o4.y = (u32)f2bf(s.x) | ((u32)f2bf(s.y) << 16);
    s = (a0[2] + a1[2] + a2[2] + a3[2]) * iv;
    o4.z = (u32)f2bf(s.x) | ((u32)f2bf(s.y) << 16);
    s = (a0[3] + a1[3] + a2[3] + a3[3]) * iv;
    o4.w = (u32)f2bf(s.x) | ((u32)f2bf(s.y) << 16);
    *(uint4*)&o.agg[(i64)row * H_ + lane] = o4;
}

// ---- x_item GEMM: fp32 A (K=256), 3-term hi/lo split, bf16 out ----
__device__ __forceinline__ void split8(const float* f, bf16x8& h, bf16x8& lo) {
#pragma unroll
    for (int i = 0; i < 8; ++i) {
        u32 b = __float_as_uint(f[i]);
        h[i] = (short)(u16)(b >> 16);
        float rem = f[i] - __uint_as_float(b & 0xffff0000u);
        lo[i] = (short)(u16)(__float_as_uint(rem) >> 16);
    }
}

__global__ __launch_bounds__(256) void mgemm_x_kernel(
    const float* __restrict__ A, const u16* __restrict__ Wh, const u16* __restrict__ Wl,
    const float* __restrict__ bias, u16* __restrict__ Cbf, int M) {
    int t = threadIdx.x;
    int w = t >> 6, l = t & 63;
    int lr = l & 15, lq = l >> 4;
    int m0 = blockIdx.x * 128 + w * 32;

    f32x4 acc[2][8];
#pragma unroll
    for (int mt = 0; mt < 2; ++mt)
#pragma unroll
        for (int nt = 0; nt < 8; ++nt) acc[mt][nt] = (f32x4){0.f, 0.f, 0.f, 0.f};

    for (int kc = 0; kc < 8; ++kc) {   // K = 256
        bf16x8 ah0, al0, ah1, al1;
        {
            int row = m0 + lr;
            float f[8];
            if (row < M) {
                const float* ap = &A[(i64)row * FEAT_ + kc * 32 + lq * 8];
                *(float4*)&f[0] = *(const float4*)ap;
                *(float4*)&f[4] = *(const float4*)(ap + 4);
            } else {
#pragma unroll
                for (int i = 0; i < 8; ++i) f[i] = 0.f;
            }
            split8(f, ah0, al0);
        }
        {
            int row = m0 + 16 + lr;
            float f[8];
            if (row < M) {
                const float* ap = &A[(i64)row * FEAT_ + kc * 32 + lq * 8];
                *(float4*)&f[0] = *(const float4*)ap;
                *(float4*)&f[4] = *(const float4*)(ap + 4);
            } else {
#pragma unroll
                for (int i = 0; i < 8; ++i) f[i] = 0.f;
            }
            split8(f, ah1, al1);
        }
        const u16* whp = Wh + ((i64)kc * 8) * 512 + (i64)l * 8;
        const u16* wlp = Wl + ((i64)kc * 8) * 512 + (i64)l * 8;
#pragma unroll
        for (int nt = 0; nt < 8; ++nt) {
            bf16x8 bh = *(const bf16x8*)(whp + nt * 512);
            bf16x8 bl = *(const bf16x8*)(wlp + nt * 512);
            acc[0][nt] = __builtin_amdgcn_mfma_f32_16x16x32_bf16(ah0, bh, acc[0][nt], 0, 0, 0);
            acc[1][nt] = __builtin_amdgcn_mfma_f32_16x16x32_bf16(ah1, bh, acc[1][nt], 0, 0, 0);
            acc[0][nt] = __builtin_amdgcn_mfma_f32_16x16x32_bf16(al0, bh, acc[0][nt], 0, 0, 0);
            acc[1][nt] = __builtin_amdgcn_mfma_f32_16x16x32_bf16(al1, bh, acc[1][nt], 0, 0, 0);
            acc[0][nt] = __builtin_amdgcn_mfma_f32_16x16x32_bf16(ah0, bl, acc[0][nt], 0, 0, 0);
            acc[1][nt] = __builtin_amdgcn_mfma_f32_16x16x32_bf16(ah1, bl, acc[1][nt], 0, 0, 0);
        }
    }
#pragma unroll
    for (int nt = 0; nt < 8; ++nt) {
        int col = nt * 16 + lr;
        float bb = bias[col];
#pragma unroll
        for (int mt = 0; mt < 2; ++mt) {
#pragma unroll
            for (int r = 0; r < 4; ++r) {
                int row = m0 + mt * 16 + (lq << 2) + r;
                if (row < M) Cbf[(i64)row * H_ + col] = f2bf(acc[mt][nt][r] + bb);
            }
        }
    }
}

// ---- packed dual GEMM kernel: bf16 A (K=128 each), single RTN bf16 W ----
struct MOp {
    const u16* A1; const u16* W1; const u16* A2; const u16* W2;
    const float* b1; const float* b2;
    float* C; u16* Cbf;
    int nblk; int n; int fuse; int pad;
};
struct MOps { MOp op[5]; };

__global__ __launch_bounds__(256) void packed_gemm_kernel(
    MOps ops, int nops,
    const float* __restrict__ alpha, const float* __restrict__ fu,
    const float* __restrict__ fi, float* __restrict__ fout,
    float* __restrict__ wout) {
    int blk = blockIdx.x;
    int i = 0;
    while (i < nops - 1 && blk >= ops.op[i].nblk) { blk -= ops.op[i].nblk; ++i; }
    MOp o = ops.op[i];
    int t = threadIdx.x;
    int w = t >> 6, l = t & 63;
    int lr = l & 15, lq = l >> 4;
    int m0 = blk * 128 + w * 32;
    int M = o.n;

    f32x4 acc[2][8];
#pragma unroll
    for (int mt = 0; mt < 2; ++mt)
#pragma unroll
        for (int nt = 0; nt < 8; ++nt) acc[mt][nt] = (f32x4){0.f, 0.f, 0.f, 0.f};

#pragma unroll
    for (int mat = 0; mat < 2; ++mat) {
        const u16* A = mat ? o.A2 : o.A1;
        const u16* W = mat ? o.W2 : o.W1;
#pragma unroll
        for (int kc = 0; kc < 4; ++kc) {   // K = 128
            bf16x8 a0 = {0, 0, 0, 0, 0, 0, 0, 0}, a1 = {0, 0, 0, 0, 0, 0, 0, 0};
            int row0 = m0 + lr, row1 = m0 + 16 + lr;
            if (row0 < M) a0 = *(const bf16x8*)&A[(i64)row0 * H_ + kc * 32 + lq * 8];
            if (row1 < M) a1 = *(const bf16x8*)&A[(i64)row1 * H_ + kc * 32 + lq * 8];
            const u16* wp = W + ((i64)kc * 8) * 512 + (i64)l * 8;
#pragma unroll
            for (int nt = 0; nt < 8; ++nt) {
                bf16x8 bw = *(const bf16x8*)(wp + nt * 512);
                acc[0][nt] = __builtin_amdgcn_mfma_f32_16x16x32_bf16(a0, bw, acc[0][nt], 0, 0, 0);
                acc[1][nt] = __builtin_amdgcn_mfma_f32_16x16x32_bf16(a1, bw, acc[1][nt], 0, 0, 0);
            }
        }
    }

    float w0 = 0.f, w1 = 0.f, w2 = 0.f;
    if (o.fuse) {
        float x0 = alpha[0], x1 = alpha[1], x2 = alpha[2];
        float mx = fmaxf(x0, fmaxf(x1, x2));
        float e0 = __expf(x0 - mx), e1 = __expf(x1 - mx), e2 = __expf(x2 - mx);
        float inv = 1.f / (e0 + e1 + e2);
        w0 = e0 * inv; w1 = e1 * inv; w2 = e2 * inv;
        if (blk == 0 && t == 0) { wout[0] = w0; wout[1] = w1; wout[2] = w2; }
    }

#pragma unroll
    for (int nt = 0; nt < 8; ++nt) {
        int col = nt * 16 + lr;
        float bb = 0.5f * (o.b1[col] + o.b2[col]);
#pragma unroll
        for (int mt = 0; mt < 2; ++mt) {
#pragma unroll
            for (int r = 0; r < 4; ++r) {
                int row = m0 + mt * 16 + (lq << 2) + r;
                if (row < M) {
                    i64 idx = (i64)row * H_ + col;
                    float v = fmaxf(0.5f * acc[mt][nt][r] + bb, 0.f);
                    if (o.C != nullptr) o.C[idx] = v;
                    if (o.Cbf != nullptr) o.Cbf[idx] = f2bf(v);
                    if (o.fuse) fout[idx] = w0 * fu[idx] + w1 * fi[idx] + w2 * v;
                }
            }
        }
    }
}

extern "C" void kernel_launch(void* const* d_in, const int* in_sizes, int n_in,
                              void* d_out, int out_size, void* d_ws, size_t ws_size,
                              hipStream_t stream) {
    const float* xif  = (const float*)d_in[0];
    const float* uemb = (const float*)d_in[1];
    const float* aemb = (const float*)d_in[2];
    const float* liW  = (const float*)d_in[3];
    const float* lib  = (const float*)d_in[4];
    const float* uiWl = (const float*)d_in[5];
    const float* uibl = (const float*)d_in[6];
    const float* uiWr = (const float*)d_in[7];
    const float* iiWl = (const float*)d_in[8];
    const float* iibl = (const float*)d_in[9];
    const float* iiWr = (const float*)d_in[10];
    const float* iaWl = (const float*)d_in[11];
    const float* iabl = (const float*)d_in[12];
    const float* iaWr = (const float*)d_in[13];
    const float* alpha = (const float*)d_in[14];
    const int* er = (const int*)d_in[15];
    const int* es = (const int*)d_in[16];
    const int* eh = (const int*)d_in[17];

    float* out = (float*)d_out;
    float* FUSED  = out;
    float* OUT_UI = out + (i64)NI_ * H_;
    float* OUT_II = out + (i64)2 * NI_ * H_;
    float* OUT_IA = out + (i64)3 * NI_ * H_;
    float* WOUT   = out + (i64)4 * NI_ * H_;

    // ---- workspace layout: bf16 region first (16B-aligned), then ints ----
    u16* u = (u16*)d_ws;
    i64 uo = 0;
    u16* WTH    = u + uo; uo += 294912;
    u16* WTL    = u + uo; uo += 294912;
    u16* X_bf   = u + uo; uo += (i64)NI_ * H_;
    u16* HIU_bf = u + uo; uo += (i64)NI_ * H_;   // UI L0 item out
    u16* HII_bf = u + uo; uo += (i64)NI_ * H_;   // II L0 item out
    u16* HIA_bf = u + uo; uo += (i64)NI_ * H_;   // IA L0 item out
    u16* HU1_bf = u + uo; uo += (i64)NU_ * H_;
    u16* HA1_bf = u + uo; uo += (i64)NA_ * H_;
    u16* UE_bf  = u + uo; uo += (i64)NU_ * H_;
    u16* AE_bf  = u + uo; uo += (i64)NA_ * H_;
    u16* AGG1 = u + uo; uo += (i64)NI_ * H_;     // rates->item (UE)
    u16* AGG2 = u + uo; uo += (i64)NU_ * H_;     // rates->user (X)
    u16* AGG3 = u + uo; uo += (i64)NI_ * H_;     // rates->item (HU1)
    u16* AGG4 = u + uo; uo += (i64)NI_ * H_;     // sim->item (X)
    u16* AGG5 = u + uo; uo += (i64)NI_ * H_;     // sim->item (HII)
    u16* AGG6 = u + uo; uo += (i64)NA_ * H_;     // has->attr (X)
    u16* AGG7 = u + uo; uo += (i64)NI_ * H_;     // has->item (AE)
    u16* AGG8 = u + uo; uo += (i64)NI_ * H_;     // has->item (HA1)

    int* ip = (int*)(u + uo);
    i64 io = 0;
    int* OFF   = ip + io; io += NTOT_ + 4;        // [0]=sentinel; off1 = OFF+1
    int* SBB   = ip + io; io += 256;
    int* SBC   = ip + io; io += 256;
    int* POOL  = ip + io; io += RTOT_;
    int* CPOOL = ip + io; io += (i64)NSB_ << 16;  // strided SB regions
    int* off1 = OFF + 1;

    // ---- weight-prep jobs ----
    const float* famWl[8] = {uiWl, uiWl, uiWl, iiWl, iiWl, iaWl, iaWl, iaWl};
    const float* famWr[8] = {uiWr, uiWr, uiWr, iiWr, iiWr, iaWr, iaWr, iaWr};
    const float* famBl[8] = {uibl, uibl, uibl, iibl, iibl, iabl, iabl, iabl};
    const int eidx[8] = {0, 1, 4, 0, 2, 0, 1, 5};
    const int sidx[8] = {3, 2, 7, 1, 3, 3, 2, 6};

    WJobs jobs;
    jobs.j[0] = {liW, nullptr, nullptr, 8, 0};
    int wtotal = 32768;
    for (int s = 0; s < 8; ++s) {
        jobs.j[1 + 2 * s] = {famWl[s] + (i64)eidx[s] * 16384, nullptr, nullptr, 7, wtotal};
        wtotal += 16384;
        jobs.j[2 + 2 * s] = {famWr[s] + (i64)eidx[s] * 16384,
                             famWl[s] + (i64)sidx[s] * 16384,
                             famWr[s] + (i64)sidx[s] * 16384, 7, wtotal};
        wtotal += 16384;
    }

    // ---- phase 1: sbinit; then binA || tobf || wsplit in ONE launch ----
    sbinit_kernel<<<1, 256, 0, stream>>>(SBC, OFF);
    long n4u = (long)NU_ * H_ / 4, n4a = (long)NA_ * H_ / 4;
    int nblkA = (RTOT_ + 4095) / 4096;               // 733
    int nblkT = (int)((n4u + n4a + 255) / 256);      // 13125
    int nblkW = (wtotal + 255) / 256;                // 1152
    packed_misc_kernel<<<nblkA + nblkT + nblkW, 256, 0, stream>>>(
        er, es, eh, SBC, CPOOL, nblkA,
        (const float4*)uemb, (ushort4*)UE_bf, n4u,
        (const float4*)aemb, (ushort4*)AE_bf, n4a, nblkT,
        jobs, wtotal, WTH, WTL);
    sbscan_kernel<<<1, 256, 0, stream>>>(SBC, SBB);
    binB_kernel<<<NSB_, 1024, 0, stream>>>(CPOOL, SBB, SBC, off1, POOL);

    // x_item = xif @ liW + lib  -> bf16 table
    mgemm_x_kernel<<<(NI_ + 127) / 128, 256, 0, stream>>>(xif, WTH, WTL, lib, X_bf, NI_);

    // ---- op builders ----
    auto mkg = [&](const u16* feat, int cbase, int n, u16* agg) {
        GOp o{};
        o.feat = feat; o.off1c = off1 + cbase; o.agg = agg;
        o.nblk = (n + 15) / 16; o.n = n;
        return o;
    };
    auto glaunch = [&](GOps& ops, int nops) {
        int grid = 0;
        for (int i = 0; i < nops; ++i) grid += ops.op[i].nblk;
        packed_gather_kernel<<<grid, 256, 0, stream>>>(ops, nops, POOL);
    };
    auto mkm = [&](int slot, const u16* agg, const u16* A2, float* C, u16* Cbf,
                   int M, int fuse) {
        MOp o{};
        o.A1 = agg;
        o.W1 = WTH + 32768 + (i64)(2 * slot) * 16384;
        o.A2 = A2;
        o.W2 = WTH + 32768 + (i64)(2 * slot + 1) * 16384;
        o.b1 = famBl[slot] + (i64)eidx[slot] * 128;
        o.b2 = famBl[slot] + (i64)sidx[slot] * 128;
        o.C = C; o.Cbf = Cbf;
        o.nblk = (M + 127) / 128; o.n = M; o.fuse = fuse;
        return o;
    };
    auto mlaunch = [&](MOps& ops, int nops) {
        int grid = 0;
        for (int i = 0; i < nops; ++i) grid += ops.op[i].nblk;
        packed_gemm_kernel<<<grid, 256, 0, stream>>>(ops, nops, alpha,
                                                     OUT_UI, OUT_II, FUSED, WOUT);
    };

    // ---- G-pack 1: all 5 layer-0 gathers (heavy rows first) ----
    {
        GOps g{};
        g.op[0] = mkg(X_bf, B_HA, NA_, AGG6);    // has->attr: 50 edges/row
        g.op[1] = mkg(UE_bf, B_RI, NI_, AGG1);   // rates->item (20/row)
        g.op[2] = mkg(X_bf, B_RU, NU_, AGG2);    // rates->user (10/row)
        g.op[3] = mkg(X_bf, B_SI, NI_, AGG4);    // sim->item (10/row)
        g.op[4] = mkg(AE_bf, B_HI, NI_, AGG7);   // has->item (5/row)
        glaunch(g, 5);
    }
    // ---- M-pack 1: all 5 layer-0 GEMMs ----
    {
        MOps m{};
        m.op[0] = mkm(1, AGG2, UE_bf, nullptr, HU1_bf, NU_, 0);
        m.op[1] = mkm(0, AGG1, X_bf, nullptr, HIU_bf, NI_, 0);
        m.op[2] = mkm(3, AGG4, X_bf, nullptr, HII_bf, NI_, 0);
        m.op[3] = mkm(6, AGG7, X_bf, nullptr, HIA_bf, NI_, 0);
        m.op[4] = mkm(5, AGG6, AE_bf, nullptr, HA1_bf, NA_, 0);
        mlaunch(m, 5);
    }
    // ---- G-pack 2: layer-1 gathers ----
    {
        GOps g{};
        g.op[0] = mkg(HU1_bf, B_RI, NI_, AGG3);
        g.op[1] = mkg(HII_bf, B_SI, NI_, AGG5);
        g.op[2] = mkg(HA1_bf, B_HI, NI_, AGG8);
        glaunch(g, 3);
    }
    // ---- M-pack 2: G2 -> OUT_UI, G4 -> OUT_II ----
    {
        MOps m{};
        m.op[0] = mkm(2, AGG3, HIU_bf, OUT_UI, nullptr, NI_, 0);
        m.op[1] = mkm(4, AGG5, HII_bf, OUT_II, nullptr, NI_, 0);
        mlaunch(m, 2);
    }
    // ---- M-pack 3: final GEMM + fused epilogue ----
    {
        MOps m{};
        m.op[0] = mkm(7, AGG8, HIA_bf, OUT_IA, nullptr, NI_, 1);
        mlaunch(m, 1);
    }
}